// Round 2
// baseline (3452.322 us; speedup 1.0000x reference)
//
#include <hip/hip_runtime.h>
#include <math.h>

typedef __attribute__((ext_vector_type(8))) __bf16 bf16x8;
typedef __attribute__((ext_vector_type(4))) float f32x4;

static __device__ __forceinline__ unsigned short f2bf(float f) {
  unsigned int u = __float_as_uint(f);
  u += 0x7FFFu + ((u >> 16) & 1u);   // RNE
  return (unsigned short)(u >> 16);
}

// edge_index accessor: mode==1 -> data is int64 (read lo word), mode==0 -> int32
static __device__ __forceinline__ int getidx(const int* __restrict__ ei, int mode, long long pos) {
  return mode ? ei[2 * pos] : ei[pos];
}

// ---------- detect int64 vs int32 edge_index (int64 hi-words are all zero) ----------
__global__ void detect_kernel(const int* __restrict__ ei, int* __restrict__ mode) {
  int lane = threadIdx.x & 63;
  int v = ei[2 * lane + 1] | ei[2 * lane + 129];
  unsigned long long nz = __ballot(v != 0);
  if (lane == 0) mode[0] = (nz == 0ull) ? 1 : 0;
}

__global__ void zero_kernel(float* __restrict__ p, long long n) {
  long long i = (long long)blockIdx.x * blockDim.x + threadIdx.x;
  if (i < n) p[i] = 0.f;
}

// ---------- scatter1: agg1[dst,:128] += x[src,:128]*w  (wave per edge, float2/lane) ----------
__global__ void scatter1_kernel(const int* __restrict__ ei, const float* __restrict__ ea,
                                const float* __restrict__ x, float* __restrict__ agg1,
                                const int* __restrict__ modep, int E) {
  const int md = modep[0];
  int e = (int)(((long long)blockIdx.x * 256 + threadIdx.x) >> 6);
  int lane = threadIdx.x & 63;
  if (e >= E) return;
  int s = getidx(ei, md, e);
  int d = getidx(ei, md, (long long)E + e);
  float w = ea[e];
  float2 v = *(const float2*)&x[(size_t)s * 128 + lane * 2];
  float* ap = &agg1[(size_t)d * 128 + lane * 2];
  atomicAdd(ap, v.x * w);
  atomicAdd(ap + 1, v.y * w);
}

// ---------- scatter2: agg2[dst,:64] += t[src,:64]*w (wave per edge, 1 float/lane) ----------
__global__ void scatter2_kernel(const int* __restrict__ ei, const float* __restrict__ ea,
                                const float* __restrict__ t, float* __restrict__ agg2,
                                const int* __restrict__ modep, int E) {
  const int md = modep[0];
  int e = (int)(((long long)blockIdx.x * 256 + threadIdx.x) >> 6);
  int lane = threadIdx.x & 63;
  if (e >= E) return;
  int s = getidx(ei, md, e);
  int d = getidx(ei, md, (long long)E + e);
  float w = ea[e];
  atomicAdd(&agg2[(size_t)d * 64 + lane], t[(size_t)s * 64 + lane] * w);
}

// ---------- generic fp32 GEMM: C[M,NC] = act(A1@W1^T + A2@W2^T + b1 + b2) ----------
__global__ void gemm_bt(const float* __restrict__ A1, const float* __restrict__ W1, int K1,
                        const float* __restrict__ A2, const float* __restrict__ W2, int K2,
                        const float* __restrict__ b1, const float* __restrict__ b2,
                        float* __restrict__ C, int NC, int doRelu) {
  __shared__ float As[64][17];
  __shared__ float Ws[64][17];
  int tid = threadIdx.x;
  int tx = tid & 15, ty = tid >> 4;
  int row0 = blockIdx.y * 64, col0 = blockIdx.x * 64;
  float acc[4][4] = {};
  for (int srcsel = 0; srcsel < 2; ++srcsel) {
    const float* A = srcsel ? A2 : A1;
    const float* W = srcsel ? W2 : W1;
    int K = srcsel ? K2 : K1;
    if (!A) continue;
    for (int kb = 0; kb < K; kb += 16) {
#pragma unroll
      for (int i = 0; i < 4; ++i) {
        int idx = tid + 256 * i;
        int r = idx >> 4, k = idx & 15;
        As[r][k] = A[(size_t)(row0 + r) * K + kb + k];
        Ws[r][k] = W[(size_t)(col0 + r) * K + kb + k];
      }
      __syncthreads();
#pragma unroll
      for (int k = 0; k < 16; ++k) {
        float a[4], w[4];
#pragma unroll
        for (int i = 0; i < 4; ++i) a[i] = As[ty * 4 + i][k];
#pragma unroll
        for (int j = 0; j < 4; ++j) w[j] = Ws[tx * 4 + j][k];
#pragma unroll
        for (int i = 0; i < 4; ++i)
#pragma unroll
          for (int j = 0; j < 4; ++j) acc[i][j] += a[i] * w[j];
      }
      __syncthreads();
    }
  }
#pragma unroll
  for (int j = 0; j < 4; ++j) {
    int c = col0 + tx * 4 + j;
    float bias = (b1 ? b1[c] : 0.f) + (b2 ? b2[c] : 0.f);
#pragma unroll
    for (int i = 0; i < 4; ++i) {
      float v = acc[i][j] + bias;
      if (doRelu) v = fmaxf(v, 0.f);
      C[(size_t)(row0 + ty * 4 + i) * NC + c] = v;
    }
  }
}

// ---------- fc1: z1[b,o] = sum_k relu(z0[b,k]) * Wfc[o,k]  (+bfc), k chunked, atomic ----------
__global__ void fc1_kernel(const float* __restrict__ z0, const float* __restrict__ Wfc,
                           const float* __restrict__ bfc, float* __restrict__ z1) {
  int b = blockIdx.y;
  int kbase = blockIdx.x * 2560;            // 25 chunks * 2560 = 64000
  int lane = threadIdx.x & 63, w = threadIdx.x >> 6;
  float zr[40];
  const float* zp = z0 + (size_t)b * 64000 + kbase;
#pragma unroll
  for (int i = 0; i < 40; ++i) zr[i] = fmaxf(zp[lane + 64 * i], 0.f);
  for (int oo = 0; oo < 16; ++oo) {
    int o = w * 16 + oo;
    const float* wp = Wfc + (size_t)o * 64000 + kbase;
    float s = 0.f;
#pragma unroll
    for (int i = 0; i < 40; ++i) s += zr[i] * wp[lane + 64 * i];
#pragma unroll
    for (int m = 1; m < 64; m <<= 1) s += __shfl_xor(s, m);
    if (lane == 0) atomicAdd(&z1[b * 64 + o], s + (kbase == 0 ? bfc[o] : 0.f));
  }
}

// ---------- fc2: z2 = relu(z1@Wfc2^T + bfc2), stored as bf16 hi + bf16 lo planes ----------
__global__ void fc2_kernel(const float* __restrict__ z1, const float* __restrict__ Wfc2,
                           const float* __restrict__ bfc2,
                           unsigned short* __restrict__ z2hi, unsigned short* __restrict__ z2lo) {
  __shared__ float z1s[4096];
  __shared__ float Ws[256][65];
  int tid = threadIdx.x;
  for (int i = tid; i < 4096; i += 256) z1s[i] = z1[i];
  int m0 = blockIdx.x * 256;
  for (int i = tid; i < 256 * 64; i += 256) {
    int r = i >> 6, j = i & 63;
    Ws[r][j] = Wfc2[(size_t)(m0 + r) * 64 + j];
  }
  __syncthreads();
  int m = m0 + tid;
  float bias = bfc2[m];
  for (int b = 0; b < 64; ++b) {
    float acc = bias;
#pragma unroll
    for (int j = 0; j < 64; ++j) acc += z1s[b * 64 + j] * Ws[tid][j];
    float v = fmaxf(acc, 0.f);
    unsigned short h = f2bf(v);
    float hf = __uint_as_float((unsigned int)h << 16);
    z2hi[(size_t)b * 64000 + m] = h;
    z2lo[(size_t)b * 64000 + m] = f2bf(v - hf);
  }
}

// ---------- decoder: per edge sigmoid(relu([z_src|z_dst]@Wd1^T + bd1) . Wd2 + bd2) ----------
// Split-bf16 (Markidis): A = Ahi+Alo, W = Whi+Wlo; acc = Ahi*Whi + Alo*Whi + Ahi*Wlo.
// 4 waves/block; wave w owns o-quarter [64w,64w+64). A-tiles XOR-swizzled in LDS.
__global__ void __launch_bounds__(256, 2)
decoder_kernel(const int* __restrict__ ei,
               const unsigned short* __restrict__ z2hi, const unsigned short* __restrict__ z2lo,
               const float* __restrict__ Wd1, const float* __restrict__ bd1,
               const float* __restrict__ Wd2, const float* __restrict__ bd2,
               float* __restrict__ out, const int* __restrict__ modep, int E) {
  __shared__ uint4 Ahi[128 * 16];    // 32 KB
  __shared__ uint4 Alo[128 * 16];    // 32 KB
  __shared__ float red[4][128];
  const int md = modep[0];
  int tid = threadIdx.x;
  int lane = tid & 63;
  int wv = tid >> 6;                 // o-quarter
  int l15 = lane & 15, g = lane >> 4;

  // register-resident B fragments (Wd1 quarter: 4 o-tiles x 4 k-blocks, hi+lo)
  bf16x8 bhi[4][4], blo[4][4];
  float wd2v[4], bd1v[4];
#pragma unroll
  for (int ot = 0; ot < 4; ++ot) {
    int o = wv * 64 + ot * 16 + l15;
    wd2v[ot] = Wd2[o];
    bd1v[ot] = bd1[o];
#pragma unroll
    for (int kb = 0; kb < 4; ++kb) {
      const float* wp = Wd1 + (size_t)o * 128 + kb * 32 + g * 8;
      bf16x8 bh, bl;
#pragma unroll
      for (int q = 0; q < 8; ++q) {
        float w = wp[q];
        unsigned short h = f2bf(w);
        float hf = __uint_as_float((unsigned int)h << 16);
        bh[q] = __uint_as_float((unsigned int)h << 16) == 0.f && h == 0 ? (__bf16)0.f : (__bf16)0.f, bh[q] = *(__bf16*)&h;
        unsigned short l = f2bf(w - hf);
        bl[q] = *(__bf16*)&l;
      }
      bhi[ot][kb] = bh;
      blo[ot][kb] = bl;
    }
  }
  float bd2v = bd2[0];

  int ntiles = E >> 7;               // E/128
  for (int tile = blockIdx.x; tile < ntiles; tile += gridDim.x) {
    __syncthreads();
    long long ebase = (long long)tile << 7;
    // gather A-tile: 128 edges x 16 chunks of 16B, hi+lo planes
#pragma unroll
    for (int c = 0; c < 8; ++c) {
      int cid = tid + 256 * c;       // 0..2047
      int e = cid >> 4, cj = cid & 15;
      long long pos = (cj & 8) ? ((long long)E + ebase + e) : (ebase + e);
      int node = getidx(ei, md, pos);
      size_t off = (size_t)node * 64 + (cj & 7) * 8;
      uint4 vh = *(const uint4*)&z2hi[off];
      uint4 vl = *(const uint4*)&z2lo[off];
      int slot = e * 16 + (cj ^ (e & 7));
      Ahi[slot] = vh;
      Alo[slot] = vl;
    }
    __syncthreads();

    float sacc[8][4];
#pragma unroll
    for (int i = 0; i < 8; ++i)
#pragma unroll
      for (int r = 0; r < 4; ++r) sacc[i][r] = 0.f;

#pragma unroll
    for (int est = 0; est < 8; ++est) {
      int row = est * 16 + l15;
      bf16x8 ah[4], al[4];
#pragma unroll
      for (int kb = 0; kb < 4; ++kb) {
        int slot = (kb * 4 + g) ^ (row & 7);
        ah[kb] = *(const bf16x8*)&Ahi[row * 16 + slot];
        al[kb] = *(const bf16x8*)&Alo[row * 16 + slot];
      }
#pragma unroll
      for (int ot = 0; ot < 4; ++ot) {
        f32x4 acc = {0.f, 0.f, 0.f, 0.f};
#pragma unroll
        for (int kb = 0; kb < 4; ++kb) {
          acc = __builtin_amdgcn_mfma_f32_16x16x32_bf16(ah[kb], bhi[ot][kb], acc, 0, 0, 0);
          acc = __builtin_amdgcn_mfma_f32_16x16x32_bf16(al[kb], bhi[ot][kb], acc, 0, 0, 0);
          acc = __builtin_amdgcn_mfma_f32_16x16x32_bf16(ah[kb], blo[ot][kb], acc, 0, 0, 0);
        }
#pragma unroll
        for (int r = 0; r < 4; ++r) {
          float p = fmaxf(acc[r] + bd1v[ot], 0.f);
          sacc[est][r] += p * wd2v[ot];   // D: col=l15 (=o), row=g*4+r (=edge)
        }
      }
    }
    // reduce over the 16 cols (l15) within each group
#pragma unroll
    for (int est = 0; est < 8; ++est)
#pragma unroll
      for (int r = 0; r < 4; ++r) {
        float s = sacc[est][r];
        s += __shfl_xor(s, 1); s += __shfl_xor(s, 2);
        s += __shfl_xor(s, 4); s += __shfl_xor(s, 8);
        sacc[est][r] = s;
      }
    if (l15 == 0) {
#pragma unroll
      for (int est = 0; est < 8; ++est)
#pragma unroll
        for (int r = 0; r < 4; ++r)
          red[wv][est * 16 + g * 4 + r] = sacc[est][r];
    }
    __syncthreads();
    if (tid < 128) {
      float s = red[0][tid] + red[1][tid] + red[2][tid] + red[3][tid] + bd2v;
      out[ebase + tid] = 1.f / (1.f + __expf(-s));
    }
  }
}

extern "C" void kernel_launch(void* const* d_in, const int* in_sizes, int n_in,
                              void* d_out, int out_size, void* d_ws, size_t ws_size,
                              hipStream_t stream) {
  const float* x    = (const float*)d_in[0];
  const int*   ei   = (const int*)d_in[1];
  const float* ea   = (const float*)d_in[2];
  const float* Wl1  = (const float*)d_in[3];
  const float* bl1  = (const float*)d_in[4];
  const float* Wr1  = (const float*)d_in[5];
  const float* br1  = (const float*)d_in[6];
  const float* Wl2  = (const float*)d_in[7];
  const float* bl2  = (const float*)d_in[8];
  const float* Wr2  = (const float*)d_in[9];
  const float* br2  = (const float*)d_in[10];
  const float* Wfc  = (const float*)d_in[11];
  const float* bfc  = (const float*)d_in[12];
  const float* Wfc2 = (const float*)d_in[13];
  const float* bfc2 = (const float*)d_in[14];
  const float* Wd1  = (const float*)d_in[15];
  const float* bd1  = (const float*)d_in[16];
  const float* Wd2  = (const float*)d_in[17];
  const float* bd2  = (const float*)d_in[18];
  float* out = (float*)d_out;

  const int N = in_sizes[0] / 128;   // 64000
  const int E = in_sizes[2];         // 2048000

  float* agg1 = (float*)d_ws;                                     // N*128
  float* z1   = agg1 + (size_t)N * 128;                           // 4096
  float* h    = z1 + 4096;                                        // N*256
  float* t    = h + (size_t)N * 256;                              // N*64 (fp32; later reused as z2 hi/lo)
  float* agg2 = t + (size_t)N * 64;                               // N*64
  int* mode   = (int*)(agg2 + (size_t)N * 64);

  // z2 hi/lo planes alias t (dead after scatter2): N*64 ushort each = N*64*4 bytes total
  unsigned short* z2hi = (unsigned short*)t;
  unsigned short* z2lo = z2hi + (size_t)N * 64;

  size_t need = ((size_t)N * 128 + 4096 + (size_t)N * 256 + (size_t)N * 128) * 4 + 64;
  if (ws_size < need || out_size < E) return;

  detect_kernel<<<1, 64, 0, stream>>>(ei, mode);
  long long nz = (long long)N * 128 + 4096;
  zero_kernel<<<(int)((nz + 255) / 256), 256, 0, stream>>>(agg1, nz);
  scatter1_kernel<<<E / 4, 256, 0, stream>>>(ei, ea, x, agg1, mode, E);
  gemm_bt<<<dim3(4, N / 64), 256, 0, stream>>>(agg1, Wl1, 128, x, Wr1, 128, bl1, br1, h, 256, 1);
  gemm_bt<<<dim3(1, N / 64), 256, 0, stream>>>(h, Wl2, 256, nullptr, nullptr, 0, nullptr, nullptr, t, 64, 0);
  gemm_bt<<<dim3(1, N / 64), 256, 0, stream>>>(h, Wr2, 256, nullptr, nullptr, 0, bl2, br2, agg2, 64, 0);
  scatter2_kernel<<<E / 4, 256, 0, stream>>>(ei, ea, t, agg2, mode, E);
  fc1_kernel<<<dim3(25, 64), 256, 0, stream>>>(agg2, Wfc, bfc, z1);
  fc2_kernel<<<250, 256, 0, stream>>>(z1, Wfc2, bfc2, z2hi, z2lo);
  decoder_kernel<<<2048, 256, 0, stream>>>(ei, z2hi, z2lo, Wd1, bd1, Wd2, bd2, out, mode, E);
}

// Round 3
// 1747.827 us; speedup vs baseline: 1.9752x; 1.9752x over previous
//
#include <hip/hip_runtime.h>
#include <math.h>

typedef __attribute__((ext_vector_type(8))) __bf16 bf16x8;
typedef __attribute__((ext_vector_type(4))) float f32x4;

static __device__ __forceinline__ unsigned short f2bf(float f) {
  unsigned int u = __float_as_uint(f);
  u += 0x7FFFu + ((u >> 16) & 1u);   // RNE
  return (unsigned short)(u >> 16);
}

// edge_index accessor: mode==1 -> data is int64 (read lo word), mode==0 -> int32
static __device__ __forceinline__ int getidx(const int* __restrict__ ei, int mode, long long pos) {
  return mode ? ei[2 * pos] : ei[pos];
}

// ---------- detect int64 vs int32 edge_index ----------
__global__ void detect_kernel(const int* __restrict__ ei, int* __restrict__ mode) {
  int lane = threadIdx.x & 63;
  int v = ei[2 * lane + 1] | ei[2 * lane + 129];
  unsigned long long nz = __ballot(v != 0);
  if (lane == 0) mode[0] = (nz == 0ull) ? 1 : 0;
}

__global__ void zero_kernel(float* __restrict__ p, long long n) {
  long long i = (long long)blockIdx.x * blockDim.x + threadIdx.x;
  if (i < n) p[i] = 0.f;
}

// ================= CSR build (counting sort by dst) =================
__global__ void hist_kernel(const int* __restrict__ ei, int* __restrict__ cnt,
                            const int* __restrict__ modep, int E) {
  const int md = modep[0];
  int e = blockIdx.x * 256 + threadIdx.x;
  if (e >= E) return;
  int d = getidx(ei, md, (long long)E + e);
  atomicAdd(&cnt[d], 1);
}

// block-local exclusive scan of 256 counters; bsum[b] = block total
__global__ void scan1_kernel(const int* __restrict__ cnt, int* __restrict__ pre,
                             int* __restrict__ bsum, int N) {
  __shared__ int ws[4];
  int i = blockIdx.x * 256 + threadIdx.x;
  int v = (i < N) ? cnt[i] : 0;
  int lane = threadIdx.x & 63, w = threadIdx.x >> 6;
  int s = v;
#pragma unroll
  for (int o = 1; o < 64; o <<= 1) { int t = __shfl_up(s, o); if (lane >= o) s += t; }
  if (lane == 63) ws[w] = s;
  __syncthreads();
  int off = 0;
  for (int k = 0; k < w; ++k) off += ws[k];
  if (i < N) pre[i] = s + off - v;
  if (threadIdx.x == 255) bsum[blockIdx.x] = s + off;
}

// single block: exclusive scan of block sums (nb <= 256)
__global__ void scan2_kernel(int* __restrict__ bsum, int nb) {
  __shared__ int ws[4];
  int i = threadIdx.x;
  int v = (i < nb) ? bsum[i] : 0;
  int lane = i & 63, w = i >> 6;
  int s = v;
#pragma unroll
  for (int o = 1; o < 64; o <<= 1) { int t = __shfl_up(s, o); if (lane >= o) s += t; }
  if (lane == 63) ws[w] = s;
  __syncthreads();
  int off = 0;
  for (int k = 0; k < w; ++k) off += ws[k];
  if (i < nb) bsum[i] = s + off - v;
}

__global__ void scan3_kernel(int* __restrict__ rowptr, const int* __restrict__ bsum,
                             int* __restrict__ fill, int N, int E) {
  int i = blockIdx.x * 256 + threadIdx.x;
  if (i < N) {
    int r = rowptr[i] + bsum[blockIdx.x];
    rowptr[i] = r;
    fill[i] = r;
  }
  if (i == 0) rowptr[N] = E;
}

__global__ void reorder_kernel(const int* __restrict__ ei, const float* __restrict__ ea,
                               int* __restrict__ fill, uint2* __restrict__ se,
                               const int* __restrict__ modep, int E) {
  const int md = modep[0];
  int e = blockIdx.x * 256 + threadIdx.x;
  if (e >= E) return;
  int s = getidx(ei, md, e);
  int d = getidx(ei, md, (long long)E + e);
  int pos = atomicAdd(&fill[d], 1);
  se[pos] = make_uint2((unsigned)s, __float_as_uint(ea[e]));
}

// ---------- CSR aggregation, conv1: agg1[n,:128] = sum_e w*x[src,:128] (wave/node) ----------
__global__ void agg1_csr_kernel(const int* __restrict__ rowptr, const uint2* __restrict__ se,
                                const float* __restrict__ x, float* __restrict__ agg1, int N) {
  int n = (int)((blockIdx.x * 256 + threadIdx.x) >> 6);
  int lane = threadIdx.x & 63;
  if (n >= N) return;
  int p = rowptr[n], end = rowptr[n + 1];
  float ax = 0.f, ay = 0.f;
  for (; p + 1 < end; p += 2) {
    uint2 e0 = se[p], e1 = se[p + 1];
    float w0 = __uint_as_float(e0.y), w1 = __uint_as_float(e1.y);
    float2 v0 = *(const float2*)&x[(size_t)e0.x * 128 + lane * 2];
    float2 v1 = *(const float2*)&x[(size_t)e1.x * 128 + lane * 2];
    ax += v0.x * w0 + v1.x * w1;
    ay += v0.y * w0 + v1.y * w1;
  }
  if (p < end) {
    uint2 e0 = se[p];
    float w0 = __uint_as_float(e0.y);
    float2 v0 = *(const float2*)&x[(size_t)e0.x * 128 + lane * 2];
    ax += v0.x * w0;
    ay += v0.y * w0;
  }
  *(float2*)&agg1[(size_t)n * 128 + lane * 2] = make_float2(ax, ay);
}

// ---------- CSR aggregation, conv2: agg2[n,:64] += sum_e w*t[src,:64] (wave/node) ----------
__global__ void agg2_csr_kernel(const int* __restrict__ rowptr, const uint2* __restrict__ se,
                                const float* __restrict__ t, float* __restrict__ agg2, int N) {
  int n = (int)((blockIdx.x * 256 + threadIdx.x) >> 6);
  int lane = threadIdx.x & 63;
  if (n >= N) return;
  int p = rowptr[n], end = rowptr[n + 1];
  float acc = 0.f;
  for (; p + 1 < end; p += 2) {
    uint2 e0 = se[p], e1 = se[p + 1];
    acc += t[(size_t)e0.x * 64 + lane] * __uint_as_float(e0.y)
         + t[(size_t)e1.x * 64 + lane] * __uint_as_float(e1.y);
  }
  if (p < end) {
    uint2 e0 = se[p];
    acc += t[(size_t)e0.x * 64 + lane] * __uint_as_float(e0.y);
  }
  agg2[(size_t)n * 64 + lane] += acc;
}

// ================= fallback atomic scatters (ws too small for CSR) =================
__global__ void scatter1_kernel(const int* __restrict__ ei, const float* __restrict__ ea,
                                const float* __restrict__ x, float* __restrict__ agg1,
                                const int* __restrict__ modep, int E) {
  const int md = modep[0];
  int e = (int)(((long long)blockIdx.x * 256 + threadIdx.x) >> 6);
  int lane = threadIdx.x & 63;
  if (e >= E) return;
  int s = getidx(ei, md, e);
  int d = getidx(ei, md, (long long)E + e);
  float w = ea[e];
  float2 v = *(const float2*)&x[(size_t)s * 128 + lane * 2];
  float* ap = &agg1[(size_t)d * 128 + lane * 2];
  atomicAdd(ap, v.x * w);
  atomicAdd(ap + 1, v.y * w);
}

__global__ void scatter2_kernel(const int* __restrict__ ei, const float* __restrict__ ea,
                                const float* __restrict__ t, float* __restrict__ agg2,
                                const int* __restrict__ modep, int E) {
  const int md = modep[0];
  int e = (int)(((long long)blockIdx.x * 256 + threadIdx.x) >> 6);
  int lane = threadIdx.x & 63;
  if (e >= E) return;
  int s = getidx(ei, md, e);
  int d = getidx(ei, md, (long long)E + e);
  float w = ea[e];
  atomicAdd(&agg2[(size_t)d * 64 + lane], t[(size_t)s * 64 + lane] * w);
}

// ---------- generic fp32 GEMM: C[M,NC] = act(A1@W1^T + A2@W2^T + b1 + b2) ----------
__global__ void gemm_bt(const float* __restrict__ A1, const float* __restrict__ W1, int K1,
                        const float* __restrict__ A2, const float* __restrict__ W2, int K2,
                        const float* __restrict__ b1, const float* __restrict__ b2,
                        float* __restrict__ C, int NC, int doRelu) {
  __shared__ float As[64][17];
  __shared__ float Ws[64][17];
  int tid = threadIdx.x;
  int tx = tid & 15, ty = tid >> 4;
  int row0 = blockIdx.y * 64, col0 = blockIdx.x * 64;
  float acc[4][4] = {};
  for (int srcsel = 0; srcsel < 2; ++srcsel) {
    const float* A = srcsel ? A2 : A1;
    const float* W = srcsel ? W2 : W1;
    int K = srcsel ? K2 : K1;
    if (!A) continue;
    for (int kb = 0; kb < K; kb += 16) {
#pragma unroll
      for (int i = 0; i < 4; ++i) {
        int idx = tid + 256 * i;
        int r = idx >> 4, k = idx & 15;
        As[r][k] = A[(size_t)(row0 + r) * K + kb + k];
        Ws[r][k] = W[(size_t)(col0 + r) * K + kb + k];
      }
      __syncthreads();
#pragma unroll
      for (int k = 0; k < 16; ++k) {
        float a[4], w[4];
#pragma unroll
        for (int i = 0; i < 4; ++i) a[i] = As[ty * 4 + i][k];
#pragma unroll
        for (int j = 0; j < 4; ++j) w[j] = Ws[tx * 4 + j][k];
#pragma unroll
        for (int i = 0; i < 4; ++i)
#pragma unroll
          for (int j = 0; j < 4; ++j) acc[i][j] += a[i] * w[j];
      }
      __syncthreads();
    }
  }
#pragma unroll
  for (int j = 0; j < 4; ++j) {
    int c = col0 + tx * 4 + j;
    float bias = (b1 ? b1[c] : 0.f) + (b2 ? b2[c] : 0.f);
#pragma unroll
    for (int i = 0; i < 4; ++i) {
      float v = acc[i][j] + bias;
      if (doRelu) v = fmaxf(v, 0.f);
      C[(size_t)(row0 + ty * 4 + i) * NC + c] = v;
    }
  }
}

// ---------- fc1: z1[b,o] += sum_k relu(z0[b,k])*Wfc[o,k]; K chunked 256/block ----------
// Wfc read exactly once. 250 blocks (1/CU), z0-chunk staged in LDS.
__global__ void __launch_bounds__(256) fc1_kernel(const float* __restrict__ z0,
                                                  const float* __restrict__ Wfc,
                                                  const float* __restrict__ bfc,
                                                  float* __restrict__ z1) {
  __shared__ float Zs[64][260];
  int tid = threadIdx.x;
  int kc = blockIdx.x;                       // 250 chunks of 256 over K=64000
  const size_t kbase = (size_t)kc * 256;
  for (int i = tid; i < 64 * 256; i += 256) {
    int b = i >> 8, k = i & 255;
    Zs[b][k] = fmaxf(z0[(size_t)b * 64000 + kbase + k], 0.f);
  }
  __syncthreads();
  int o = tid >> 2, q = tid & 3;
  float acc[16];
#pragma unroll
  for (int j = 0; j < 16; ++j) acc[j] = 0.f;
  const float* wp = Wfc + (size_t)o * 64000 + kbase;
  for (int k = 0; k < 256; k += 4) {
    float4 w = *(const float4*)&wp[k];
#pragma unroll
    for (int j = 0; j < 16; ++j) {
      float4 z = *(const float4*)&Zs[q * 16 + j][k];
      acc[j] += z.x * w.x + z.y * w.y + z.z * w.z + z.w * w.w;
    }
  }
  float bias = (kc == 0) ? bfc[o] : 0.f;
#pragma unroll
  for (int j = 0; j < 16; ++j)
    atomicAdd(&z1[(q * 16 + j) * 64 + o], acc[j] + bias);
}

// ---------- fc2: z2 = relu(z1@Wfc2^T + bfc2), stored as bf16 hi + bf16 lo planes ----------
__global__ void fc2_kernel(const float* __restrict__ z1, const float* __restrict__ Wfc2,
                           const float* __restrict__ bfc2,
                           unsigned short* __restrict__ z2hi, unsigned short* __restrict__ z2lo) {
  __shared__ float z1s[4096];
  __shared__ float Ws[256][65];
  int tid = threadIdx.x;
  for (int i = tid; i < 4096; i += 256) z1s[i] = z1[i];
  int m0 = blockIdx.x * 256;
  for (int i = tid; i < 256 * 64; i += 256) {
    int r = i >> 6, j = i & 63;
    Ws[r][j] = Wfc2[(size_t)(m0 + r) * 64 + j];
  }
  __syncthreads();
  int m = m0 + tid;
  float bias = bfc2[m];
  for (int b = 0; b < 64; ++b) {
    float acc = bias;
#pragma unroll
    for (int j = 0; j < 64; ++j) acc += z1s[b * 64 + j] * Ws[tid][j];
    float v = fmaxf(acc, 0.f);
    unsigned short h = f2bf(v);
    float hf = __uint_as_float((unsigned int)h << 16);
    z2hi[(size_t)b * 64000 + m] = h;
    z2lo[(size_t)b * 64000 + m] = f2bf(v - hf);
  }
}

// ---------- decoder: split-bf16 MFMA, 4 waves/block, A-tiles XOR-swizzled LDS ----------
__global__ void __launch_bounds__(256, 2)
decoder_kernel(const int* __restrict__ ei,
               const unsigned short* __restrict__ z2hi, const unsigned short* __restrict__ z2lo,
               const float* __restrict__ Wd1, const float* __restrict__ bd1,
               const float* __restrict__ Wd2, const float* __restrict__ bd2,
               float* __restrict__ out, const int* __restrict__ modep, int E) {
  __shared__ uint4 Ahi[128 * 16];    // 32 KB
  __shared__ uint4 Alo[128 * 16];    // 32 KB
  __shared__ float red[4][128];
  const int md = modep[0];
  int tid = threadIdx.x;
  int lane = tid & 63;
  int wv = tid >> 6;
  int l15 = lane & 15, g = lane >> 4;

  bf16x8 bhi[4][4], blo[4][4];
  float wd2v[4], bd1v[4];
#pragma unroll
  for (int ot = 0; ot < 4; ++ot) {
    int o = wv * 64 + ot * 16 + l15;
    wd2v[ot] = Wd2[o];
    bd1v[ot] = bd1[o];
#pragma unroll
    for (int kb = 0; kb < 4; ++kb) {
      const float* wp = Wd1 + (size_t)o * 128 + kb * 32 + g * 8;
      bf16x8 bh, bl;
#pragma unroll
      for (int q = 0; q < 8; ++q) {
        float w = wp[q];
        unsigned short h = f2bf(w);
        float hf = __uint_as_float((unsigned int)h << 16);
        bh[q] = *(__bf16*)&h;
        unsigned short l = f2bf(w - hf);
        bl[q] = *(__bf16*)&l;
      }
      bhi[ot][kb] = bh;
      blo[ot][kb] = bl;
    }
  }
  float bd2v = bd2[0];

  int ntiles = E >> 7;
  for (int tile = blockIdx.x; tile < ntiles; tile += gridDim.x) {
    __syncthreads();
    long long ebase = (long long)tile << 7;
#pragma unroll
    for (int c = 0; c < 8; ++c) {
      int cid = tid + 256 * c;
      int e = cid >> 4, cj = cid & 15;
      long long pos = (cj & 8) ? ((long long)E + ebase + e) : (ebase + e);
      int node = getidx(ei, md, pos);
      size_t off = (size_t)node * 64 + (cj & 7) * 8;
      uint4 vh = *(const uint4*)&z2hi[off];
      uint4 vl = *(const uint4*)&z2lo[off];
      int slot = e * 16 + (cj ^ (e & 7));
      Ahi[slot] = vh;
      Alo[slot] = vl;
    }
    __syncthreads();

    float sacc[8][4];
#pragma unroll
    for (int i = 0; i < 8; ++i)
#pragma unroll
      for (int r = 0; r < 4; ++r) sacc[i][r] = 0.f;

#pragma unroll
    for (int est = 0; est < 8; ++est) {
      int row = est * 16 + l15;
      bf16x8 ah[4], al[4];
#pragma unroll
      for (int kb = 0; kb < 4; ++kb) {
        int slot = (kb * 4 + g) ^ (row & 7);
        ah[kb] = *(const bf16x8*)&Ahi[row * 16 + slot];
        al[kb] = *(const bf16x8*)&Alo[row * 16 + slot];
      }
#pragma unroll
      for (int ot = 0; ot < 4; ++ot) {
        f32x4 acc = {0.f, 0.f, 0.f, 0.f};
#pragma unroll
        for (int kb = 0; kb < 4; ++kb) {
          acc = __builtin_amdgcn_mfma_f32_16x16x32_bf16(ah[kb], bhi[ot][kb], acc, 0, 0, 0);
          acc = __builtin_amdgcn_mfma_f32_16x16x32_bf16(al[kb], bhi[ot][kb], acc, 0, 0, 0);
          acc = __builtin_amdgcn_mfma_f32_16x16x32_bf16(ah[kb], blo[ot][kb], acc, 0, 0, 0);
        }
#pragma unroll
        for (int r = 0; r < 4; ++r) {
          float p = fmaxf(acc[r] + bd1v[ot], 0.f);
          sacc[est][r] += p * wd2v[ot];
        }
      }
    }
#pragma unroll
    for (int est = 0; est < 8; ++est)
#pragma unroll
      for (int r = 0; r < 4; ++r) {
        float s = sacc[est][r];
        s += __shfl_xor(s, 1); s += __shfl_xor(s, 2);
        s += __shfl_xor(s, 4); s += __shfl_xor(s, 8);
        sacc[est][r] = s;
      }
    if (l15 == 0) {
#pragma unroll
      for (int est = 0; est < 8; ++est)
#pragma unroll
        for (int r = 0; r < 4; ++r)
          red[wv][est * 16 + g * 4 + r] = sacc[est][r];
    }
    __syncthreads();
    if (tid < 128) {
      float s = red[0][tid] + red[1][tid] + red[2][tid] + red[3][tid] + bd2v;
      out[ebase + tid] = 1.f / (1.f + __expf(-s));
    }
  }
}

extern "C" void kernel_launch(void* const* d_in, const int* in_sizes, int n_in,
                              void* d_out, int out_size, void* d_ws, size_t ws_size,
                              hipStream_t stream) {
  const float* x    = (const float*)d_in[0];
  const int*   ei   = (const int*)d_in[1];
  const float* ea   = (const float*)d_in[2];
  const float* Wl1  = (const float*)d_in[3];
  const float* bl1  = (const float*)d_in[4];
  const float* Wr1  = (const float*)d_in[5];
  const float* br1  = (const float*)d_in[6];
  const float* Wl2  = (const float*)d_in[7];
  const float* bl2  = (const float*)d_in[8];
  const float* Wr2  = (const float*)d_in[9];
  const float* br2  = (const float*)d_in[10];
  const float* Wfc  = (const float*)d_in[11];
  const float* bfc  = (const float*)d_in[12];
  const float* Wfc2 = (const float*)d_in[13];
  const float* bfc2 = (const float*)d_in[14];
  const float* Wd1  = (const float*)d_in[15];
  const float* bd1  = (const float*)d_in[16];
  const float* Wd2  = (const float*)d_in[17];
  const float* bd2  = (const float*)d_in[18];
  float* out = (float*)d_out;

  const int N = in_sizes[0] / 128;   // 64000
  const int E = in_sizes[2];         // 2048000
  const int NB = (N + 255) / 256;    // 250 scan blocks

  float* agg1 = (float*)d_ws;                                     // N*128
  float* z1   = agg1 + (size_t)N * 128;                           // 4096
  float* h    = z1 + 4096;                                        // N*256
  float* t    = h + (size_t)N * 256;                              // N*64 (later z2 hi/lo)
  float* agg2 = t + (size_t)N * 64;                               // N*64
  uint2* se   = (uint2*)(agg2 + (size_t)N * 64);                  // E uint2
  int* cnt    = (int*)(se + E);                                   // N
  int* rowptr = cnt + N;                                          // N+1
  int* fill   = rowptr + N + 1;                                   // N
  int* bsum   = fill + N;                                         // 256
  int* mode_csr = bsum + 256;

  unsigned short* z2hi = (unsigned short*)t;
  unsigned short* z2lo = z2hi + (size_t)N * 64;

  size_t base = ((size_t)N * 128 + 4096 + (size_t)N * 256 + (size_t)N * 128) * 4;
  size_t need_old = base + 64;
  size_t need_csr = base + (size_t)E * 8 + ((size_t)3 * N + 300) * 4;
  if (ws_size < need_old || out_size < E) return;
  bool use_csr = (ws_size >= need_csr);
  int* mode = use_csr ? mode_csr : (int*)(se);

  detect_kernel<<<1, 64, 0, stream>>>(ei, mode);

  if (use_csr) {
    zero_kernel<<<17, 256, 0, stream>>>(z1, 4096);
    zero_kernel<<<NB, 256, 0, stream>>>((float*)cnt, N);   // zero bits == int 0
    hist_kernel<<<(E + 255) / 256, 256, 0, stream>>>(ei, cnt, mode, E);
    scan1_kernel<<<NB, 256, 0, stream>>>(cnt, rowptr, bsum, N);
    scan2_kernel<<<1, 256, 0, stream>>>(bsum, NB);
    scan3_kernel<<<NB, 256, 0, stream>>>(rowptr, bsum, fill, N, E);
    reorder_kernel<<<(E + 255) / 256, 256, 0, stream>>>(ei, ea, fill, se, mode, E);
    agg1_csr_kernel<<<(N + 3) / 4, 256, 0, stream>>>(rowptr, se, x, agg1, N);
  } else {
    long long nz = (long long)N * 128 + 4096;
    zero_kernel<<<(int)((nz + 255) / 256), 256, 0, stream>>>(agg1, nz);
    scatter1_kernel<<<E / 4, 256, 0, stream>>>(ei, ea, x, agg1, mode, E);
  }

  gemm_bt<<<dim3(4, N / 64), 256, 0, stream>>>(agg1, Wl1, 128, x, Wr1, 128, bl1, br1, h, 256, 1);
  gemm_bt<<<dim3(1, N / 64), 256, 0, stream>>>(h, Wl2, 256, nullptr, nullptr, 0, nullptr, nullptr, t, 64, 0);
  gemm_bt<<<dim3(1, N / 64), 256, 0, stream>>>(h, Wr2, 256, nullptr, nullptr, 0, bl2, br2, agg2, 64, 0);

  if (use_csr) {
    agg2_csr_kernel<<<(N + 3) / 4, 256, 0, stream>>>(rowptr, se, t, agg2, N);
  } else {
    scatter2_kernel<<<E / 4, 256, 0, stream>>>(ei, ea, t, agg2, mode, E);
  }

  fc1_kernel<<<250, 256, 0, stream>>>(agg2, Wfc, bfc, z1);
  fc2_kernel<<<250, 256, 0, stream>>>(z1, Wfc2, bfc2, z2hi, z2lo);
  decoder_kernel<<<2048, 256, 0, stream>>>(ei, z2hi, z2lo, Wd1, bd1, Wd2, bd2, out, mode, E);
}

// Round 4
// 1626.117 us; speedup vs baseline: 2.1230x; 1.0748x over previous
//
#include <hip/hip_runtime.h>
#include <math.h>

typedef __attribute__((ext_vector_type(8))) __bf16 bf16x8;
typedef __attribute__((ext_vector_type(4))) float f32x4;

static __device__ __forceinline__ unsigned short f2bf(float f) {
  unsigned int u = __float_as_uint(f);
  u += 0x7FFFu + ((u >> 16) & 1u);   // RNE
  return (unsigned short)(u >> 16);
}

// edge_index accessor: mode==1 -> data is int64 (read lo word), mode==0 -> int32
static __device__ __forceinline__ int getidx(const int* __restrict__ ei, int mode, long long pos) {
  return mode ? ei[2 * pos] : ei[pos];
}

// ---------- detect int64 vs int32 edge_index ----------
__global__ void detect_kernel(const int* __restrict__ ei, int* __restrict__ mode) {
  int lane = threadIdx.x & 63;
  int v = ei[2 * lane + 1] | ei[2 * lane + 129];
  unsigned long long nz = __ballot(v != 0);
  if (lane == 0) mode[0] = (nz == 0ull) ? 1 : 0;
}

__global__ void zero_kernel(float* __restrict__ p, long long n) {
  long long i = (long long)blockIdx.x * blockDim.x + threadIdx.x;
  if (i < n) p[i] = 0.f;
}

// ================= CSR build (counting sort by dst) =================
__global__ void hist_kernel(const int* __restrict__ ei, int* __restrict__ cnt,
                            const int* __restrict__ modep, int E) {
  const int md = modep[0];
  int e = blockIdx.x * 256 + threadIdx.x;
  if (e >= E) return;
  int d = getidx(ei, md, (long long)E + e);
  atomicAdd(&cnt[d], 1);
}

__global__ void scan1_kernel(const int* __restrict__ cnt, int* __restrict__ pre,
                             int* __restrict__ bsum, int N) {
  __shared__ int ws[4];
  int i = blockIdx.x * 256 + threadIdx.x;
  int v = (i < N) ? cnt[i] : 0;
  int lane = threadIdx.x & 63, w = threadIdx.x >> 6;
  int s = v;
#pragma unroll
  for (int o = 1; o < 64; o <<= 1) { int t = __shfl_up(s, o); if (lane >= o) s += t; }
  if (lane == 63) ws[w] = s;
  __syncthreads();
  int off = 0;
  for (int k = 0; k < w; ++k) off += ws[k];
  if (i < N) pre[i] = s + off - v;
  if (threadIdx.x == 255) bsum[blockIdx.x] = s + off;
}

__global__ void scan2_kernel(int* __restrict__ bsum, int nb) {
  __shared__ int ws[4];
  int i = threadIdx.x;
  int v = (i < nb) ? bsum[i] : 0;
  int lane = i & 63, w = i >> 6;
  int s = v;
#pragma unroll
  for (int o = 1; o < 64; o <<= 1) { int t = __shfl_up(s, o); if (lane >= o) s += t; }
  if (lane == 63) ws[w] = s;
  __syncthreads();
  int off = 0;
  for (int k = 0; k < w; ++k) off += ws[k];
  if (i < nb) bsum[i] = s + off - v;
}

__global__ void scan3_kernel(int* __restrict__ rowptr, const int* __restrict__ bsum,
                             int* __restrict__ fill, int N, int E) {
  int i = blockIdx.x * 256 + threadIdx.x;
  if (i < N) {
    int r = rowptr[i] + bsum[blockIdx.x];
    rowptr[i] = r;
    fill[i] = r;
  }
  if (i == 0) rowptr[N] = E;
}

// reorder: se[pos]=(src,w); optionally edst[pos]=dst, eorig[pos]=orig edge id
__global__ void reorder_kernel(const int* __restrict__ ei, const float* __restrict__ ea,
                               int* __restrict__ fill, uint2* __restrict__ se,
                               int* __restrict__ edst, int* __restrict__ eorig,
                               const int* __restrict__ modep, int E, int wantDec) {
  const int md = modep[0];
  int e = blockIdx.x * 256 + threadIdx.x;
  if (e >= E) return;
  int s = getidx(ei, md, e);
  int d = getidx(ei, md, (long long)E + e);
  int pos = atomicAdd(&fill[d], 1);
  se[pos] = make_uint2((unsigned)s, __float_as_uint(ea[e]));
  if (wantDec) {
    edst[pos] = d;
    eorig[pos] = e;
  }
}

// ---------- CSR aggregation, conv1 ----------
__global__ void agg1_csr_kernel(const int* __restrict__ rowptr, const uint2* __restrict__ se,
                                const float* __restrict__ x, float* __restrict__ agg1, int N) {
  int n = (int)((blockIdx.x * 256 + threadIdx.x) >> 6);
  int lane = threadIdx.x & 63;
  if (n >= N) return;
  int p = rowptr[n], end = rowptr[n + 1];
  float ax = 0.f, ay = 0.f;
  for (; p + 1 < end; p += 2) {
    uint2 e0 = se[p], e1 = se[p + 1];
    float w0 = __uint_as_float(e0.y), w1 = __uint_as_float(e1.y);
    float2 v0 = *(const float2*)&x[(size_t)e0.x * 128 + lane * 2];
    float2 v1 = *(const float2*)&x[(size_t)e1.x * 128 + lane * 2];
    ax += v0.x * w0 + v1.x * w1;
    ay += v0.y * w0 + v1.y * w1;
  }
  if (p < end) {
    uint2 e0 = se[p];
    float w0 = __uint_as_float(e0.y);
    float2 v0 = *(const float2*)&x[(size_t)e0.x * 128 + lane * 2];
    ax += v0.x * w0;
    ay += v0.y * w0;
  }
  *(float2*)&agg1[(size_t)n * 128 + lane * 2] = make_float2(ax, ay);
}

// ---------- CSR aggregation, conv2 ----------
__global__ void agg2_csr_kernel(const int* __restrict__ rowptr, const uint2* __restrict__ se,
                                const float* __restrict__ t, float* __restrict__ agg2, int N) {
  int n = (int)((blockIdx.x * 256 + threadIdx.x) >> 6);
  int lane = threadIdx.x & 63;
  if (n >= N) return;
  int p = rowptr[n], end = rowptr[n + 1];
  float acc = 0.f;
  for (; p + 1 < end; p += 2) {
    uint2 e0 = se[p], e1 = se[p + 1];
    acc += t[(size_t)e0.x * 64 + lane] * __uint_as_float(e0.y)
         + t[(size_t)e1.x * 64 + lane] * __uint_as_float(e1.y);
  }
  if (p < end) {
    uint2 e0 = se[p];
    acc += t[(size_t)e0.x * 64 + lane] * __uint_as_float(e0.y);
  }
  agg2[(size_t)n * 64 + lane] += acc;
}

// ================= fallback atomic scatters =================
__global__ void scatter1_kernel(const int* __restrict__ ei, const float* __restrict__ ea,
                                const float* __restrict__ x, float* __restrict__ agg1,
                                const int* __restrict__ modep, int E) {
  const int md = modep[0];
  int e = (int)(((long long)blockIdx.x * 256 + threadIdx.x) >> 6);
  int lane = threadIdx.x & 63;
  if (e >= E) return;
  int s = getidx(ei, md, e);
  int d = getidx(ei, md, (long long)E + e);
  float w = ea[e];
  float2 v = *(const float2*)&x[(size_t)s * 128 + lane * 2];
  float* ap = &agg1[(size_t)d * 128 + lane * 2];
  atomicAdd(ap, v.x * w);
  atomicAdd(ap + 1, v.y * w);
}

__global__ void scatter2_kernel(const int* __restrict__ ei, const float* __restrict__ ea,
                                const float* __restrict__ t, float* __restrict__ agg2,
                                const int* __restrict__ modep, int E) {
  const int md = modep[0];
  int e = (int)(((long long)blockIdx.x * 256 + threadIdx.x) >> 6);
  int lane = threadIdx.x & 63;
  if (e >= E) return;
  int s = getidx(ei, md, e);
  int d = getidx(ei, md, (long long)E + e);
  float w = ea[e];
  atomicAdd(&agg2[(size_t)d * 64 + lane], t[(size_t)s * 64 + lane] * w);
}

// ---------- generic fp32 GEMM ----------
__global__ void gemm_bt(const float* __restrict__ A1, const float* __restrict__ W1, int K1,
                        const float* __restrict__ A2, const float* __restrict__ W2, int K2,
                        const float* __restrict__ b1, const float* __restrict__ b2,
                        float* __restrict__ C, int NC, int doRelu) {
  __shared__ float As[64][17];
  __shared__ float Ws[64][17];
  int tid = threadIdx.x;
  int tx = tid & 15, ty = tid >> 4;
  int row0 = blockIdx.y * 64, col0 = blockIdx.x * 64;
  float acc[4][4] = {};
  for (int srcsel = 0; srcsel < 2; ++srcsel) {
    const float* A = srcsel ? A2 : A1;
    const float* W = srcsel ? W2 : W1;
    int K = srcsel ? K2 : K1;
    if (!A) continue;
    for (int kb = 0; kb < K; kb += 16) {
#pragma unroll
      for (int i = 0; i < 4; ++i) {
        int idx = tid + 256 * i;
        int r = idx >> 4, k = idx & 15;
        As[r][k] = A[(size_t)(row0 + r) * K + kb + k];
        Ws[r][k] = W[(size_t)(col0 + r) * K + kb + k];
      }
      __syncthreads();
#pragma unroll
      for (int k = 0; k < 16; ++k) {
        float a[4], w[4];
#pragma unroll
        for (int i = 0; i < 4; ++i) a[i] = As[ty * 4 + i][k];
#pragma unroll
        for (int j = 0; j < 4; ++j) w[j] = Ws[tx * 4 + j][k];
#pragma unroll
        for (int i = 0; i < 4; ++i)
#pragma unroll
          for (int j = 0; j < 4; ++j) acc[i][j] += a[i] * w[j];
      }
      __syncthreads();
    }
  }
#pragma unroll
  for (int j = 0; j < 4; ++j) {
    int c = col0 + tx * 4 + j;
    float bias = (b1 ? b1[c] : 0.f) + (b2 ? b2[c] : 0.f);
#pragma unroll
    for (int i = 0; i < 4; ++i) {
      float v = acc[i][j] + bias;
      if (doRelu) v = fmaxf(v, 0.f);
      C[(size_t)(row0 + ty * 4 + i) * NC + c] = v;
    }
  }
}

// ---------- fc1 ----------
__global__ void __launch_bounds__(256) fc1_kernel(const float* __restrict__ z0,
                                                  const float* __restrict__ Wfc,
                                                  const float* __restrict__ bfc,
                                                  float* __restrict__ z1) {
  __shared__ float Zs[64][260];
  int tid = threadIdx.x;
  int kc = blockIdx.x;
  const size_t kbase = (size_t)kc * 256;
  for (int i = tid; i < 64 * 256; i += 256) {
    int b = i >> 8, k = i & 255;
    Zs[b][k] = fmaxf(z0[(size_t)b * 64000 + kbase + k], 0.f);
  }
  __syncthreads();
  int o = tid >> 2, q = tid & 3;
  float acc[16];
#pragma unroll
  for (int j = 0; j < 16; ++j) acc[j] = 0.f;
  const float* wp = Wfc + (size_t)o * 64000 + kbase;
  for (int k = 0; k < 256; k += 4) {
    float4 w = *(const float4*)&wp[k];
#pragma unroll
    for (int j = 0; j < 16; ++j) {
      float4 z = *(const float4*)&Zs[q * 16 + j][k];
      acc[j] += z.x * w.x + z.y * w.y + z.z * w.z + z.w * w.w;
    }
  }
  float bias = (kc == 0) ? bfc[o] : 0.f;
#pragma unroll
  for (int j = 0; j < 16; ++j)
    atomicAdd(&z1[(q * 16 + j) * 64 + o], acc[j] + bias);
}

// ---------- fc2: z2 packed per node: [node][0..63]=hi, [64..127]=lo (ushort) ----------
__global__ void fc2_kernel(const float* __restrict__ z1, const float* __restrict__ Wfc2,
                           const float* __restrict__ bfc2,
                           unsigned short* __restrict__ z2p, int nPerB) {
  __shared__ float z1s[4096];
  __shared__ float Ws[256][65];
  int tid = threadIdx.x;
  for (int i = tid; i < 4096; i += 256) z1s[i] = z1[i];
  int m0 = blockIdx.x * 256;
  for (int i = tid; i < 256 * 64; i += 256) {
    int r = i >> 6, j = i & 63;
    Ws[r][j] = Wfc2[(size_t)(m0 + r) * 64 + j];
  }
  __syncthreads();
  int m = m0 + tid;
  float bias = bfc2[m];
  int ninb = m >> 6, feat = m & 63;
  for (int b = 0; b < 64; ++b) {
    float acc = bias;
#pragma unroll
    for (int j = 0; j < 64; ++j) acc += z1s[b * 64 + j] * Ws[tid][j];
    float v = fmaxf(acc, 0.f);
    unsigned short hh = f2bf(v);
    float hf = __uint_as_float((unsigned int)hh << 16);
    size_t node = (size_t)b * nPerB + ninb;
    z2p[node * 128 + feat] = hh;
    z2p[node * 128 + 64 + feat] = f2bf(v - hf);
  }
}

// ---------- decoder: split-bf16 MFMA; sorted (dst-CSR order) or original order ----------
// LDS rows padded to 17 uint4 (272B): read = 2 lanes/bank-quartet (free),
// write = uniform over 8 quartets (b128 floor). 71.7KB LDS -> 2 blocks/CU.
__global__ void __launch_bounds__(256, 2)
decoder_kernel(const uint2* __restrict__ se, const int* __restrict__ edst,
               const int* __restrict__ eorig, const int* __restrict__ ei,
               const unsigned short* __restrict__ z2p,
               const float* __restrict__ Wd1, const float* __restrict__ bd1,
               const float* __restrict__ Wd2, const float* __restrict__ bd2,
               float* __restrict__ out, const int* __restrict__ modep,
               int E, int sorted) {
  __shared__ uint4 Ahi[128 * 17];
  __shared__ uint4 Alo[128 * 17];
  __shared__ float red[4][128];
  const int md = modep[0];
  int tid = threadIdx.x;
  int lane = tid & 63;
  int wv = tid >> 6;
  int l15 = lane & 15, g = lane >> 4;

  bf16x8 bhi[4][4], blo[4][4];
  float wd2v[4], bd1v[4];
#pragma unroll
  for (int ot = 0; ot < 4; ++ot) {
    int o = wv * 64 + ot * 16 + l15;
    wd2v[ot] = Wd2[o];
    bd1v[ot] = bd1[o];
#pragma unroll
    for (int kb = 0; kb < 4; ++kb) {
      const float* wp = Wd1 + (size_t)o * 128 + kb * 32 + g * 8;
      bf16x8 bh, bl;
#pragma unroll
      for (int q = 0; q < 8; ++q) {
        float w = wp[q];
        unsigned short hh = f2bf(w);
        float hf = __uint_as_float((unsigned int)hh << 16);
        bh[q] = *(__bf16*)&hh;
        unsigned short ll = f2bf(w - hf);
        bl[q] = *(__bf16*)&ll;
      }
      bhi[ot][kb] = bh;
      blo[ot][kb] = bl;
    }
  }
  float bd2v = bd2[0];

  int ntiles = E >> 7;
  int tpb = (ntiles + gridDim.x - 1) / gridDim.x;
  int tA = blockIdx.x * tpb;
  int tB = min(tA + tpb, ntiles);
  int e = tid >> 1, side = tid & 1;

  for (int tile = tA; tile < tB; ++tile) {
    long long ebase = (long long)tile << 7;
    long long p = ebase + e;
    int node = sorted ? (side ? edst[p] : (int)se[p].x)
                      : getidx(ei, md, side ? (long long)E + p : p);
    const uint4* zp = (const uint4*)(z2p + (size_t)node * 128);
    int base = e * 17 + side * 8;
#pragma unroll
    for (int q = 0; q < 8; ++q) Ahi[base + q] = zp[q];
#pragma unroll
    for (int q = 0; q < 8; ++q) Alo[base + q] = zp[8 + q];
    __syncthreads();

    float sacc[8][4];
#pragma unroll
    for (int i = 0; i < 8; ++i)
#pragma unroll
      for (int r = 0; r < 4; ++r) sacc[i][r] = 0.f;

#pragma unroll
    for (int est = 0; est < 8; ++est) {
      int row = est * 16 + l15;
      bf16x8 ah[4], al[4];
#pragma unroll
      for (int kb = 0; kb < 4; ++kb) {
        ah[kb] = *(const bf16x8*)&Ahi[row * 17 + kb * 4 + g];
        al[kb] = *(const bf16x8*)&Alo[row * 17 + kb * 4 + g];
      }
#pragma unroll
      for (int ot = 0; ot < 4; ++ot) {
        f32x4 acc = {0.f, 0.f, 0.f, 0.f};
#pragma unroll
        for (int kb = 0; kb < 4; ++kb) {
          acc = __builtin_amdgcn_mfma_f32_16x16x32_bf16(ah[kb], bhi[ot][kb], acc, 0, 0, 0);
          acc = __builtin_amdgcn_mfma_f32_16x16x32_bf16(al[kb], bhi[ot][kb], acc, 0, 0, 0);
          acc = __builtin_amdgcn_mfma_f32_16x16x32_bf16(ah[kb], blo[ot][kb], acc, 0, 0, 0);
        }
#pragma unroll
        for (int r = 0; r < 4; ++r) {
          float pp = fmaxf(acc[r] + bd1v[ot], 0.f);
          sacc[est][r] += pp * wd2v[ot];
        }
      }
    }
#pragma unroll
    for (int est = 0; est < 8; ++est)
#pragma unroll
      for (int r = 0; r < 4; ++r) {
        float s = sacc[est][r];
        s += __shfl_xor(s, 1); s += __shfl_xor(s, 2);
        s += __shfl_xor(s, 4); s += __shfl_xor(s, 8);
        sacc[est][r] = s;
      }
    if (l15 == 0) {
#pragma unroll
      for (int est = 0; est < 8; ++est)
#pragma unroll
        for (int r = 0; r < 4; ++r)
          red[wv][est * 16 + g * 4 + r] = sacc[est][r];
    }
    __syncthreads();
    if (tid < 128) {
      float s = red[0][tid] + red[1][tid] + red[2][tid] + red[3][tid] + bd2v;
      long long q0 = ebase + tid;
      int oid = sorted ? eorig[q0] : (int)q0;
      out[oid] = 1.f / (1.f + __expf(-s));
    }
  }
}

extern "C" void kernel_launch(void* const* d_in, const int* in_sizes, int n_in,
                              void* d_out, int out_size, void* d_ws, size_t ws_size,
                              hipStream_t stream) {
  const float* x    = (const float*)d_in[0];
  const int*   ei   = (const int*)d_in[1];
  const float* ea   = (const float*)d_in[2];
  const float* Wl1  = (const float*)d_in[3];
  const float* bl1  = (const float*)d_in[4];
  const float* Wr1  = (const float*)d_in[5];
  const float* br1  = (const float*)d_in[6];
  const float* Wl2  = (const float*)d_in[7];
  const float* bl2  = (const float*)d_in[8];
  const float* Wr2  = (const float*)d_in[9];
  const float* br2  = (const float*)d_in[10];
  const float* Wfc  = (const float*)d_in[11];
  const float* bfc  = (const float*)d_in[12];
  const float* Wfc2 = (const float*)d_in[13];
  const float* bfc2 = (const float*)d_in[14];
  const float* Wd1  = (const float*)d_in[15];
  const float* bd1  = (const float*)d_in[16];
  const float* Wd2  = (const float*)d_in[17];
  const float* bd2  = (const float*)d_in[18];
  float* out = (float*)d_out;

  const int N = in_sizes[0] / 128;   // 64000
  const int E = in_sizes[2];         // 2048000
  const int NB = (N + 255) / 256;

  float* agg1 = (float*)d_ws;                                     // N*128
  float* z1   = agg1 + (size_t)N * 128;                           // 4096
  float* h    = z1 + 4096;                                        // N*256
  float* t    = h + (size_t)N * 256;                              // N*64 (later z2p: N*128 ushort)
  float* agg2 = t + (size_t)N * 64;                               // N*64
  uint2* se   = (uint2*)(agg2 + (size_t)N * 64);                  // E uint2
  int* cnt    = (int*)(se + E);                                   // N
  int* rowptr = cnt + N;                                          // N+1
  int* fill   = rowptr + N + 1;                                   // N
  int* bsum   = fill + N;                                         // 256
  int* mode_csr = bsum + 256;                                     // 1
  int* edst   = mode_csr + 4;                                     // E
  int* eorig  = edst + E;                                         // E

  unsigned short* z2p = (unsigned short*)t;

  size_t base = ((size_t)N * 128 + 4096 + (size_t)N * 256 + (size_t)N * 128) * 4;
  size_t need_old  = base + 64;
  size_t need_csr  = base + (size_t)E * 8 + ((size_t)3 * N + 300) * 4;
  size_t need_csr2 = need_csr + (size_t)E * 8 + 64;
  if (ws_size < need_old || out_size < E) return;
  bool use_csr  = (ws_size >= need_csr);
  bool use_csr2 = (ws_size >= need_csr2);
  int* mode = use_csr ? mode_csr : (int*)(se);

  detect_kernel<<<1, 64, 0, stream>>>(ei, mode);

  if (use_csr) {
    zero_kernel<<<17, 256, 0, stream>>>(z1, 4096);
    zero_kernel<<<NB, 256, 0, stream>>>((float*)cnt, N);
    hist_kernel<<<(E + 255) / 256, 256, 0, stream>>>(ei, cnt, mode, E);
    scan1_kernel<<<NB, 256, 0, stream>>>(cnt, rowptr, bsum, N);
    scan2_kernel<<<1, 256, 0, stream>>>(bsum, NB);
    scan3_kernel<<<NB, 256, 0, stream>>>(rowptr, bsum, fill, N, E);
    reorder_kernel<<<(E + 255) / 256, 256, 0, stream>>>(ei, ea, fill, se, edst, eorig,
                                                        mode, E, use_csr2 ? 1 : 0);
    agg1_csr_kernel<<<(N + 3) / 4, 256, 0, stream>>>(rowptr, se, x, agg1, N);
  } else {
    long long nz = (long long)N * 128 + 4096;
    zero_kernel<<<(int)((nz + 255) / 256), 256, 0, stream>>>(agg1, nz);
    scatter1_kernel<<<E / 4, 256, 0, stream>>>(ei, ea, x, agg1, mode, E);
  }

  gemm_bt<<<dim3(4, N / 64), 256, 0, stream>>>(agg1, Wl1, 128, x, Wr1, 128, bl1, br1, h, 256, 1);
  gemm_bt<<<dim3(1, N / 64), 256, 0, stream>>>(h, Wl2, 256, nullptr, nullptr, 0, nullptr, nullptr, t, 64, 0);
  gemm_bt<<<dim3(1, N / 64), 256, 0, stream>>>(h, Wr2, 256, nullptr, nullptr, 0, bl2, br2, agg2, 64, 0);

  if (use_csr) {
    agg2_csr_kernel<<<(N + 3) / 4, 256, 0, stream>>>(rowptr, se, t, agg2, N);
  } else {
    scatter2_kernel<<<E / 4, 256, 0, stream>>>(ei, ea, t, agg2, mode, E);
  }

  fc1_kernel<<<250, 256, 0, stream>>>(agg2, Wfc, bfc, z1);
  fc2_kernel<<<250, 256, 0, stream>>>(z1, Wfc2, bfc2, z2p, N / 64);
  decoder_kernel<<<2048, 256, 0, stream>>>(se, edst, eorig, ei, z2p,
                                           Wd1, bd1, Wd2, bd2, out, mode, E,
                                           use_csr2 ? 1 : 0);
}